// Round 5
// baseline (124.136 us; speedup 1.0000x reference)
//
#include <hip/hip_runtime.h>

// Selection (pos/neg thresholds, argmax ties) must match the numpy f32
// reference bit-for-bit. Disable FMA contraction so "sum - a*b" is never
// fused differently than numpy evaluates it.
#pragma clang fp contract(off)

#define GMAX 256

__device__ __forceinline__ unsigned int ordf(float f) {
    unsigned int u = __float_as_uint(f);
    return (u & 0x80000000u) ? ~u : (u | 0x80000000u);
}

// Fused kernel. Phase 1 (all blocks): block = 4 waves, 64 RoIs; wave w covers
// gts [64w,64w+64). Exact threshold predicates in double replace the IEEE f32
// divide:
//   fl32(a/b) >= 0.5f  <=>  a >= C1*b   (C1 = (2^25-1)/2^26, tie->even->0.5)
//   fl32(a/b) >= 0.1f  <=>  a >  C2*b   (C2 = 26843545/2^28, tie->even->pred)
// C*(double)b is a 25x24-bit product => exact in double => predicates exact.
// Phase 2 (last block per image, counter-elected): scan ballot masks -> first
// 16 pos / 64 neg indices; exact argmax (divide, reference tie semantics) for
// the 64 selected RoIs; write outputs. GTs are already staged in this block's
// LDS from phase 1.
__global__ __launch_bounds__(256) void fused_kernel(
    const float* __restrict__ rois, const float* __restrict__ gts,
    const int* __restrict__ labels,
    unsigned long long* __restrict__ pmask, unsigned long long* __restrict__ nmask,
    int* __restrict__ counters,
    float* __restrict__ out, int R, int G, int B, int NW)
{
    const int bi   = blockIdx.y;
    const int tid  = threadIdx.x;
    const int lane = tid & 63;
    const int wave = tid >> 6;
    const int r    = blockIdx.x * 64 + lane;

    __shared__ float4 gbox[GMAX];
    __shared__ float  garea[GMAX];
    __shared__ unsigned long long bp4[4], ba4[4];
    __shared__ int lastflag;

    // stage all gts (invalid / absent -> marker box 4.0: inter=0, area=0)
    for (int t = tid; t < GMAX; t += 256) {
        float a = 4.f, b = 4.f, c = 4.f, d = 4.f, area = 0.f;
        if (t < G) {
            const float4 g4 = *reinterpret_cast<const float4*>(gts + ((size_t)bi * G + t) * 4);
            const float s = 1.0f / 1024.0f;       // exact (power of two)
            const float na = g4.x * s, nb = g4.y * s, nc = g4.z * s, nd = g4.w * s;
            if ((na != 0.f) || (nb != 0.f) || (nc != 0.f) || (nd != 0.f)) {
                a = na; b = nb; c = nc; d = nd;
                area = fmaxf(nc - na, 0.f) * fmaxf(nd - nb, 0.f);
            }
        }
        gbox[t]  = make_float4(a, b, c, d);
        garea[t] = area;
    }
    __syncthreads();

    float4 rr = make_float4(0.f, 0.f, 0.f, 0.f);
    if (r < R) rr = *reinterpret_cast<const float4*>(rois + ((size_t)bi * R + r) * 4);
    const bool rv = (r < R) &&
        ((rr.x != 0.f) || (rr.y != 0.f) || (rr.z != 0.f) || (rr.w != 0.f));
    const float ar = fmaxf(rr.z - rr.x, 0.f) * fmaxf(rr.w - rr.y, 0.f);

    const double C1 = 33554431.0 / 67108864.0;    // 0.5  - 2^-26 (exact)
    const double C2 = 26843545.0 / 268435456.0;   // 0.1f - 2^-28 (exact)
    bool anyp = false, any1 = false;

    {
        const int gbase = wave << 6;
        #pragma unroll 4
        for (int j = 0; j < 64; ++j) {
            const int g = gbase + j;              // wave-uniform -> LDS broadcast
            const float4 gb = gbox[g];
            const float y1 = fmaxf(rr.x, gb.x);
            const float x1 = fmaxf(rr.y, gb.y);
            const float y2 = fminf(rr.z, gb.z);
            const float x2 = fminf(rr.w, gb.w);
            const float inter = fmaxf(y2 - y1, 0.f) * fmaxf(x2 - x1, 0.f);
            const float uni   = (ar + garea[g]) - inter;   // reference op order
            const double A  = (double)inter;
            const double Bd = (double)fmaxf(uni, 1e-7f);
            anyp = anyp | (A >= C1 * Bd);
            any1 = any1 | (A >  C2 * Bd);
        }
    }

    const unsigned long long brv = __ballot(rv);  // identical in every wave
    bp4[wave] = __ballot(anyp);
    ba4[wave] = __ballot(any1);
    __syncthreads();

    if (tid == 0) {
        const unsigned long long por = bp4[0] | bp4[1] | bp4[2] | bp4[3];
        const unsigned long long aor = ba4[0] | ba4[1] | ba4[2] | ba4[3];
        __hip_atomic_store(&pmask[(size_t)bi * NW + blockIdx.x], brv & por,
                           __ATOMIC_RELAXED, __HIP_MEMORY_SCOPE_AGENT);
        __hip_atomic_store(&nmask[(size_t)bi * NW + blockIdx.x], brv & aor & ~por,
                           __ATOMIC_RELAXED, __HIP_MEMORY_SCOPE_AGENT);
        __builtin_amdgcn_fence(__ATOMIC_RELEASE, "agent");
        const int old = __hip_atomic_fetch_add(&counters[bi], 1,
                           __ATOMIC_RELAXED, __HIP_MEMORY_SCOPE_AGENT);
        lastflag = (old == NW - 1) ? 1 : 0;
    }
    __syncthreads();
    if (!lastflag) return;

    // ---- phase 2: this is the last block for image bi ----
    __builtin_amdgcn_fence(__ATOMIC_ACQUIRE, "agent");

    const unsigned long long* pm = pmask + (size_t)bi * NW;
    const unsigned long long* nm = nmask + (size_t)bi * NW;
    const int w0 = 2 * tid, w1 = 2 * tid + 1;     // supports NW <= 512
    unsigned long long mp0 = 0, mp1 = 0, mn0 = 0, mn1 = 0;
    if (w0 < NW) {
        mp0 = __hip_atomic_load(&pm[w0], __ATOMIC_RELAXED, __HIP_MEMORY_SCOPE_AGENT);
        mn0 = __hip_atomic_load(&nm[w0], __ATOMIC_RELAXED, __HIP_MEMORY_SCOPE_AGENT);
    }
    if (w1 < NW) {
        mp1 = __hip_atomic_load(&pm[w1], __ATOMIC_RELAXED, __HIP_MEMORY_SCOPE_AGENT);
        mn1 = __hip_atomic_load(&nm[w1], __ATOMIC_RELAXED, __HIP_MEMORY_SCOPE_AGENT);
    }
    const int cp0 = __popcll(mp0), cp1 = __popcll(mp1);
    const int cn0 = __popcll(mn0), cn1 = __popcll(mn1);

    // packed (pos<<16 | neg) inclusive scan: 6-step wave shfl + 4-wave combine
    int packed = ((cp0 + cp1) << 16) | (cn0 + cn1);
    int incl = packed;
    #pragma unroll
    for (int d = 1; d < 64; d <<= 1) {
        const int v = __shfl_up(incl, d, 64);
        if (lane >= d) incl += v;
    }
    __shared__ int wsum[4];
    if (lane == 63) wsum[wave] = incl;
    __syncthreads();
    int wpre = 0;
    #pragma unroll
    for (int wv = 0; wv < 4; ++wv) if (wv < wave) wpre += wsum[wv];
    incl += wpre;
    const int excl = incl - packed;
    const int tot  = wsum[0] + wsum[1] + wsum[2] + wsum[3];
    const int totp = tot >> 16;
    const int totn = tot & 0xFFFF;

    __shared__ int plist[16], nlist[64];
    {
        int rank = excl >> 16;
        unsigned long long m = mp0;
        while (m && rank < 16) { const int b = __ffsll(m) - 1; plist[rank++] = w0 * 64 + b; m &= m - 1; }
        rank = (excl >> 16) + cp0; m = mp1;
        while (m && rank < 16) { const int b = __ffsll(m) - 1; plist[rank++] = w1 * 64 + b; m &= m - 1; }
        rank = excl & 0xFFFF; m = mn0;
        while (m && rank < 64) { const int b = __ffsll(m) - 1; nlist[rank++] = w0 * 64 + b; m &= m - 1; }
        rank = (excl & 0xFFFF) + cn0; m = mn1;
        while (m && rank < 64) { const int b = __ffsll(m) - 1; nlist[rank++] = w1 * 64 + b; m &= m - 1; }
    }
    __syncthreads();

    const int n_pos = min(totp, 16);
    const int n_neg = min(totn, 64 - n_pos);

    __shared__ int sridx[64];
    __shared__ unsigned long long skey[64];
    if (tid < 64) {
        const bool isp = tid < n_pos;
        const bool isn = (!isp) && (tid < n_pos + n_neg);
        sridx[tid] = isp ? plist[tid] : (isn ? nlist[tid - n_pos] : 0);
        skey[tid]  = 0ull;
    }
    __syncthreads();

    // exact argmax for each selected roi: 4 threads/slot, 64 gts each
    {
        const int slot = tid >> 2;
        const int sub  = tid & 3;
        const int ridx = sridx[slot];
        const float4 rb = *reinterpret_cast<const float4*>(rois + ((size_t)bi * R + ridx) * 4);
        const float arb = fmaxf(rb.z - rb.x, 0.f) * fmaxf(rb.w - rb.y, 0.f);
        float best = -1.0f;
        int bidx = sub * 64;
        for (int j = 0; j < 64; ++j) {
            const int g = sub * 64 + j;
            const float4 gb = gbox[g];
            const float y1 = fmaxf(rb.x, gb.x);
            const float x1 = fmaxf(rb.y, gb.y);
            const float y2 = fminf(rb.z, gb.z);
            const float x2 = fminf(rb.w, gb.w);
            const float inter = fmaxf(y2 - y1, 0.f) * fmaxf(x2 - x1, 0.f);
            const float uni = (arb + garea[g]) - inter;
            float v = inter / fmaxf(uni, 1e-7f);  // IEEE f32 divide, as reference
            if (gb.x == 4.f) v = -1.0f;           // invalid / absent gt -> -1
            if (v > best) { best = v; bidx = g; } // strict > = first occurrence
        }
        // merge partials: larger float wins, lower g wins float ties
        const unsigned long long key =
            ((unsigned long long)ordf(best) << 32) | (unsigned int)(~(unsigned int)bidx);
        atomicMax(&skey[slot], key);
    }
    __syncthreads();

    if (tid < 64) {
        const int slot = tid;
        const bool isp = slot < n_pos;
        const bool isn = (!isp) && (slot < n_pos + n_neg);
        const int ridx = sridx[slot];
        const int gidx = (int)(~(unsigned int)(skey[slot] & 0xFFFFFFFFull));

        const float4 rb = *reinterpret_cast<const float4*>(rois + ((size_t)bi * R + ridx) * 4);
        const float4 gb = gbox[gidx];
        const float vf = (isp || isn) ? 1.0f : 0.0f;
        const float eps = 1e-7f;

        const float rh  = fmaxf(rb.z - rb.x, eps);
        const float rw  = fmaxf(rb.w - rb.y, eps);
        const float rcy = rb.x + 0.5f * rh;
        const float rcx = rb.y + 0.5f * rw;
        const float gh  = fmaxf(gb.z - gb.x, eps);
        const float gw  = fmaxf(gb.w - gb.y, eps);
        const float gcy = gb.x + 0.5f * gh;
        const float gcx = gb.y + 0.5f * gw;

        float o0 = (gcy - rcy) / rh;
        float o1 = (gcx - rcx) / rw;
        float o2 = logf(gh / rh);
        float o3 = logf(gw / rw);
        o0 = (o0 * vf) / 0.1f;
        o1 = (o1 * vf) / 0.1f;
        o2 = (o2 * vf) / 0.2f;
        o3 = (o3 * vf) / 0.2f;

        const int base = bi * 64 + slot;
        reinterpret_cast<float4*>(out)[base] = make_float4(rb.x * vf, rb.y * vf, rb.z * vf, rb.w * vf);
        reinterpret_cast<float4*>(out + (size_t)B * 256)[base] = make_float4(o0, o1, o2, o3);
        out[(size_t)B * 512 + base] = isp ? (float)labels[(size_t)bi * G + gidx] : 0.0f;
    }
}

extern "C" void kernel_launch(void* const* d_in, const int* in_sizes, int n_in,
                              void* d_out, int out_size, void* d_ws, size_t ws_size,
                              hipStream_t stream)
{
    const float* rois   = (const float*)d_in[0];
    const float* gts    = (const float*)d_in[1];
    const int*   labels = (const int*)d_in[2];
    float* out = (float*)d_out;

    const int B = out_size / 576;            // 64*4 + 64*4 + 64 per image
    const int G = in_sizes[2] / B;
    const int R = in_sizes[0] / (4 * B);
    const int NW = (R + 63) / 64;            // one mask word per 64 RoIs

    unsigned long long* pmask = (unsigned long long*)d_ws;
    unsigned long long* nmask = pmask + (size_t)B * NW;
    int* counters = (int*)(nmask + (size_t)B * NW);

    (void)hipMemsetAsync(counters, 0, (size_t)B * sizeof(int), stream);
    dim3 grid(NW, B);                        // block handles 64 RoIs
    fused_kernel<<<grid, 256, 0, stream>>>(rois, gts, labels, pmask, nmask,
                                           counters, out, R, G, B, NW);
}

// Round 6
// 99.548 us; speedup vs baseline: 1.2470x; 1.2470x over previous
//
#include <hip/hip_runtime.h>

// Selection (pos/neg thresholds, argmax ties) must match the numpy f32
// reference bit-for-bit. Disable FMA contraction so "sum - a*b" is never
// fused differently than numpy evaluates it.
#pragma clang fp contract(off)

#define GMAX 256

__device__ __forceinline__ unsigned int ordf(float f) {
    unsigned int u = __float_as_uint(f);
    return (u & 0x80000000u) ? ~u : (u | 0x80000000u);
}

// Kernel 1: block = 4 waves, 64 RoIs; wave w covers gts [64w,64w+64).
// Exact threshold predicates in double replace the IEEE f32 divide:
//   fl32(a/b) >= 0.5f  <=>  a >= C1*b   (C1 = (2^25-1)/2^26, tie->even->0.5)
//   fl32(a/b) >= 0.1f  <=>  a >  C2*b   (C2 = 26843545/2^28, tie->even->pred)
// C*(double)b is a 25x24-bit product => exact in double => predicates exact.
// gt area is recomputed from the staged box (bit-identical to reference's
// area_g) instead of a second LDS read.
__global__ __launch_bounds__(256) void iou_cls_kernel(
    const float* __restrict__ rois, const float* __restrict__ gts,
    unsigned long long* __restrict__ pmask, unsigned long long* __restrict__ nmask,
    int R, int G, int NW)
{
    const int bi   = blockIdx.y;
    const int tid  = threadIdx.x;
    const int lane = tid & 63;
    const int wave = tid >> 6;
    const int r    = blockIdx.x * 64 + lane;

    __shared__ float4 gbox[GMAX];
    __shared__ unsigned long long bp4[4], ba4[4];

    // stage all gts (invalid / absent -> marker box 4.0: inter=0, area=0)
    for (int t = tid; t < GMAX; t += 256) {
        float a = 4.f, b = 4.f, c = 4.f, d = 4.f;
        if (t < G) {
            const float4 g4 = *reinterpret_cast<const float4*>(gts + ((size_t)bi * G + t) * 4);
            const float s = 1.0f / 1024.0f;       // exact (power of two)
            const float na = g4.x * s, nb = g4.y * s, nc = g4.z * s, nd = g4.w * s;
            if ((na != 0.f) || (nb != 0.f) || (nc != 0.f) || (nd != 0.f)) {
                a = na; b = nb; c = nc; d = nd;
            }
        }
        gbox[t] = make_float4(a, b, c, d);
    }
    __syncthreads();

    float4 rr = make_float4(0.f, 0.f, 0.f, 0.f);
    if (r < R) rr = *reinterpret_cast<const float4*>(rois + ((size_t)bi * R + r) * 4);
    const bool rv = (r < R) &&
        ((rr.x != 0.f) || (rr.y != 0.f) || (rr.z != 0.f) || (rr.w != 0.f));
    const float ar = fmaxf(rr.z - rr.x, 0.f) * fmaxf(rr.w - rr.y, 0.f);

    const double C1 = 33554431.0 / 67108864.0;    // 0.5  - 2^-26 (exact)
    const double C2 = 26843545.0 / 268435456.0;   // 0.1f - 2^-28 (exact)
    bool anyp = false, any1 = false;

    {
        const int gbase = wave << 6;
        #pragma unroll 8
        for (int j = 0; j < 64; ++j) {
            const float4 gb = gbox[gbase + j];    // wave-uniform -> LDS broadcast
            const float y1 = fmaxf(rr.x, gb.x);
            const float x1 = fmaxf(rr.y, gb.y);
            const float y2 = fminf(rr.z, gb.z);
            const float x2 = fminf(rr.w, gb.w);
            const float inter = fmaxf(y2 - y1, 0.f) * fmaxf(x2 - x1, 0.f);
            const float ga = fmaxf(gb.z - gb.x, 0.f) * fmaxf(gb.w - gb.y, 0.f);
            const float uni = (ar + ga) - inter;  // reference op order
            const double A  = (double)inter;
            const double Bd = (double)fmaxf(uni, 1e-7f);
            anyp = anyp | (A >= C1 * Bd);
            any1 = any1 | (A >  C2 * Bd);
        }
    }

    const unsigned long long brv = __ballot(rv);  // identical in every wave
    bp4[wave] = __ballot(anyp);
    ba4[wave] = __ballot(any1);
    __syncthreads();

    if (tid == 0) {
        const unsigned long long por = bp4[0] | bp4[1] | bp4[2] | bp4[3];
        const unsigned long long aor = ba4[0] | ba4[1] | ba4[2] | ba4[3];
        pmask[(size_t)bi * NW + blockIdx.x] = brv & por;
        nmask[(size_t)bi * NW + blockIdx.x] = brv & aor & ~por;
    }
}

// Kernel 2: per image (8 blocks x 256 threads): shfl-scan of ballot masks ->
// first 16 pos / 64 neg indices; exact argmax (divide, reference tie
// semantics) for the 64 selected RoIs; write outputs.
__global__ __launch_bounds__(256) void select_kernel(
    const float* __restrict__ rois, const float* __restrict__ gts,
    const int* __restrict__ labels,
    const unsigned long long* __restrict__ pmask, const unsigned long long* __restrict__ nmask,
    float* __restrict__ out, int R, int G, int B, int NW)
{
    const int bi   = blockIdx.x;
    const int tid  = threadIdx.x;
    const int lane = tid & 63;
    const int wave = tid >> 6;

    __shared__ float4 gbox[GMAX];
    __shared__ int wsum[4];
    __shared__ int plist[16], nlist[64];
    __shared__ int sridx[64];
    __shared__ unsigned long long skey[64];

    // stage normalized gts (marker 4.0 for invalid/absent)
    for (int t = tid; t < GMAX; t += 256) {
        float a = 4.f, b = 4.f, c = 4.f, d = 4.f;
        if (t < G) {
            const float4 g4 = *reinterpret_cast<const float4*>(gts + ((size_t)bi * G + t) * 4);
            const float s = 1.0f / 1024.0f;
            const float na = g4.x * s, nb = g4.y * s, nc = g4.z * s, nd = g4.w * s;
            if ((na != 0.f) || (nb != 0.f) || (nc != 0.f) || (nd != 0.f)) {
                a = na; b = nb; c = nc; d = nd;
            }
        }
        gbox[t] = make_float4(a, b, c, d);
    }
    if (tid < 16) plist[tid] = 0;
    if (tid < 64) { nlist[tid] = 0; skey[tid] = 0ull; }

    const unsigned long long* pm = pmask + (size_t)bi * NW;
    const unsigned long long* nm = nmask + (size_t)bi * NW;
    const int w0 = 2 * tid, w1 = 2 * tid + 1;     // supports NW <= 512
    unsigned long long mp0 = 0, mp1 = 0, mn0 = 0, mn1 = 0;
    if (w0 < NW) { mp0 = pm[w0]; mn0 = nm[w0]; }
    if (w1 < NW) { mp1 = pm[w1]; mn1 = nm[w1]; }
    const int cp0 = __popcll(mp0), cp1 = __popcll(mp1);
    const int cn0 = __popcll(mn0), cn1 = __popcll(mn1);

    // packed (pos<<16 | neg) inclusive scan: 6-step wave shfl + 4-wave combine
    const int packed = ((cp0 + cp1) << 16) | (cn0 + cn1);
    int incl = packed;
    #pragma unroll
    for (int d = 1; d < 64; d <<= 1) {
        const int v = __shfl_up(incl, d, 64);
        if (lane >= d) incl += v;
    }
    if (lane == 63) wsum[wave] = incl;
    __syncthreads();
    int wpre = 0;
    #pragma unroll
    for (int wv = 0; wv < 4; ++wv) if (wv < wave) wpre += wsum[wv];
    incl += wpre;
    const int excl = incl - packed;
    const int tot  = wsum[0] + wsum[1] + wsum[2] + wsum[3];
    const int totp = tot >> 16;
    const int totn = tot & 0xFFFF;

    {
        int rank = excl >> 16;
        unsigned long long m = mp0;
        while (m && rank < 16) { const int b = __ffsll(m) - 1; plist[rank++] = w0 * 64 + b; m &= m - 1; }
        rank = (excl >> 16) + cp0; m = mp1;
        while (m && rank < 16) { const int b = __ffsll(m) - 1; plist[rank++] = w1 * 64 + b; m &= m - 1; }
        rank = excl & 0xFFFF; m = mn0;
        while (m && rank < 64) { const int b = __ffsll(m) - 1; nlist[rank++] = w0 * 64 + b; m &= m - 1; }
        rank = (excl & 0xFFFF) + cn0; m = mn1;
        while (m && rank < 64) { const int b = __ffsll(m) - 1; nlist[rank++] = w1 * 64 + b; m &= m - 1; }
    }
    __syncthreads();

    const int n_pos = min(totp, 16);
    const int n_neg = min(totn, 64 - n_pos);

    if (tid < 64) {
        const bool isp = tid < n_pos;
        const bool isn = (!isp) && (tid < n_pos + n_neg);
        sridx[tid] = isp ? plist[tid] : (isn ? nlist[tid - n_pos] : 0);
    }
    __syncthreads();

    // exact argmax for each selected roi: 4 threads/slot, 64 gts each
    {
        const int slot = tid >> 2;
        const int sub  = tid & 3;
        const int ridx = sridx[slot];
        const float4 rb = *reinterpret_cast<const float4*>(rois + ((size_t)bi * R + ridx) * 4);
        const float arb = fmaxf(rb.z - rb.x, 0.f) * fmaxf(rb.w - rb.y, 0.f);
        float best = -1.0f;
        int bidx = sub * 64;
        for (int j = 0; j < 64; ++j) {
            const int g = sub * 64 + j;
            const float4 gb = gbox[g];
            const float y1 = fmaxf(rb.x, gb.x);
            const float x1 = fmaxf(rb.y, gb.y);
            const float y2 = fminf(rb.z, gb.z);
            const float x2 = fminf(rb.w, gb.w);
            const float inter = fmaxf(y2 - y1, 0.f) * fmaxf(x2 - x1, 0.f);
            const float ga = fmaxf(gb.z - gb.x, 0.f) * fmaxf(gb.w - gb.y, 0.f);
            const float uni = (arb + ga) - inter;
            float v = inter / fmaxf(uni, 1e-7f);  // IEEE f32 divide, as reference
            if (gb.x == 4.f) v = -1.0f;           // invalid / absent gt -> -1
            if (v > best) { best = v; bidx = g; } // strict > = first occurrence
        }
        // merge partials: larger float wins, lower g wins float ties
        const unsigned long long key =
            ((unsigned long long)ordf(best) << 32) | (unsigned int)(~(unsigned int)bidx);
        atomicMax(&skey[slot], key);
    }
    __syncthreads();

    if (tid < 64) {
        const int slot = tid;
        const bool isp = slot < n_pos;
        const bool isn = (!isp) && (slot < n_pos + n_neg);
        const int ridx = sridx[slot];
        const int gidx = (int)(~(unsigned int)(skey[slot] & 0xFFFFFFFFull));

        const float4 rb = *reinterpret_cast<const float4*>(rois + ((size_t)bi * R + ridx) * 4);
        const float4 gb = gbox[gidx];
        const float vf = (isp || isn) ? 1.0f : 0.0f;
        const float eps = 1e-7f;

        const float rh  = fmaxf(rb.z - rb.x, eps);
        const float rw  = fmaxf(rb.w - rb.y, eps);
        const float rcy = rb.x + 0.5f * rh;
        const float rcx = rb.y + 0.5f * rw;
        const float gh  = fmaxf(gb.z - gb.x, eps);
        const float gw  = fmaxf(gb.w - gb.y, eps);
        const float gcy = gb.x + 0.5f * gh;
        const float gcx = gb.y + 0.5f * gw;

        float o0 = (gcy - rcy) / rh;
        float o1 = (gcx - rcx) / rw;
        float o2 = logf(gh / rh);
        float o3 = logf(gw / rw);
        o0 = (o0 * vf) / 0.1f;
        o1 = (o1 * vf) / 0.1f;
        o2 = (o2 * vf) / 0.2f;
        o3 = (o3 * vf) / 0.2f;

        const int base = bi * 64 + slot;
        reinterpret_cast<float4*>(out)[base] = make_float4(rb.x * vf, rb.y * vf, rb.z * vf, rb.w * vf);
        reinterpret_cast<float4*>(out + (size_t)B * 256)[base] = make_float4(o0, o1, o2, o3);
        out[(size_t)B * 512 + base] = isp ? (float)labels[(size_t)bi * G + gidx] : 0.0f;
    }
}

extern "C" void kernel_launch(void* const* d_in, const int* in_sizes, int n_in,
                              void* d_out, int out_size, void* d_ws, size_t ws_size,
                              hipStream_t stream)
{
    const float* rois   = (const float*)d_in[0];
    const float* gts    = (const float*)d_in[1];
    const int*   labels = (const int*)d_in[2];
    float* out = (float*)d_out;

    const int B = out_size / 576;            // 64*4 + 64*4 + 64 per image
    const int G = in_sizes[2] / B;
    const int R = in_sizes[0] / (4 * B);
    const int NW = (R + 63) / 64;            // one mask word per 64 RoIs

    unsigned long long* pmask = (unsigned long long*)d_ws;
    unsigned long long* nmask = pmask + (size_t)B * NW;

    dim3 grid(NW, B);                        // block handles 64 RoIs
    iou_cls_kernel<<<grid, 256, 0, stream>>>(rois, gts, pmask, nmask, R, G, NW);
    select_kernel<<<B, 256, 0, stream>>>(rois, gts, labels, pmask, nmask, out, R, G, B, NW);
}